// Round 1
// baseline (346.046 us; speedup 1.0000x reference)
//
#include <hip/hip_runtime.h>
#include <math.h>

#define N_NODES 20000
#define N_EDGES 320000
#define EMB 128
#define HID 512          // 4*EMB
#define PQ_STRIDE 1024   // P (512) + Q (512) per node

// ---------------------------------------------------------------------------
// float atomic max via int/uint monotone bit trick (init must be -inf)
// ---------------------------------------------------------------------------
__device__ __forceinline__ void atomicMaxFloat(float* addr, float v) {
    if (v >= 0.0f) {
        atomicMax((int*)addr, __float_as_int(v));
    } else {
        atomicMin((unsigned int*)addr, __float_as_uint(v));
    }
}

// ---------------------------------------------------------------------------
// init per-node reduction buffers (ws is poisoned 0xAA before every launch)
// ---------------------------------------------------------------------------
__global__ void init_nodes(float* __restrict__ node_max, float* __restrict__ node_sum) {
    int i = blockIdx.x * 256 + threadIdx.x;
    if (i < N_NODES) {
        node_max[i] = -INFINITY;
        node_sum[i] = 0.0f;
    }
}

// ---------------------------------------------------------------------------
// GEMM: PQ[n, 0:512]   = sum_k h[n,k] * W1[k,      :]   (P)
//       PQ[n, 512:1024]= sum_k h[n,k] * W1[128+k,  :]   (Q)
// M=20000, K=128, N=1024.  f32 vector ALU (no fp32 MFMA on CDNA4).
// Tile 64x64, BK=16, 256 threads, 4x4 micro-tile per thread.
// ---------------------------------------------------------------------------
#define TM 64
#define TN 64
#define BK 16

__global__ __launch_bounds__(256) void gemm_pq(
    const float* __restrict__ h, const float* __restrict__ W1,
    float* __restrict__ PQ)
{
    // As padded to stride 68 floats: keeps float4 reads 16B-aligned and the
    // transposed store at worst 2-way bank-aliased (free on gfx950).
    __shared__ float As[BK][TM + 4];
    __shared__ float Bs[BK][TN];

    const int tid = threadIdx.x;
    const int nt  = blockIdx.x;           // 0..15  (column tile of 64 over 1024)
    const int mt  = blockIdx.y;           // 0..312 (row tile of 64 over 20000)
    const int m_base = mt * TM;

    // staging thread mapping
    const int a_m = tid >> 2;             // 0..63
    const int a_k = (tid & 3) << 2;       // 0,4,8,12
    const int b_k = tid >> 4;             // 0..15
    const int b_n = (tid & 15) << 2;      // 0..60

    // compute thread mapping
    const int ty = tid >> 4;              // 0..15
    const int tx = tid & 15;              // 0..15
    const int cm = ty << 2;
    const int cn = tx << 2;

    float acc[4][4] = {};

    const int  row_a = m_base + a_m;
    const bool a_ok  = row_a < N_NODES;

    // which half of W1 feeds this column tile (512 % 64 == 0 so a tile never straddles)
    const int w_row_off = (nt < 8) ? 0 : 128;
    const int w_col     = ((nt & 7) << 6) + b_n;

    for (int k0 = 0; k0 < EMB; k0 += BK) {
        float4 av = make_float4(0.f, 0.f, 0.f, 0.f);
        if (a_ok) av = *(const float4*)(h + (size_t)row_a * EMB + k0 + a_k);
        As[a_k + 0][a_m] = av.x;
        As[a_k + 1][a_m] = av.y;
        As[a_k + 2][a_m] = av.z;
        As[a_k + 3][a_m] = av.w;

        float4 bv = *(const float4*)(W1 + (size_t)(w_row_off + k0 + b_k) * HID + w_col);
        *(float4*)&Bs[b_k][b_n] = bv;

        __syncthreads();
#pragma unroll
        for (int kk = 0; kk < BK; ++kk) {
            float a[4], b[4];
            *(float4*)a = *(const float4*)&As[kk][cm];
            *(float4*)b = *(const float4*)&Bs[kk][cn];
#pragma unroll
            for (int i = 0; i < 4; ++i)
#pragma unroll
                for (int j = 0; j < 4; ++j)
                    acc[i][j] = fmaf(a[i], b[j], acc[i][j]);
        }
        __syncthreads();
    }

    const int col_base = nt * TN + cn;
#pragma unroll
    for (int i = 0; i < 4; ++i) {
        int r = m_base + cm + i;
        if (r < N_NODES) {
            *(float4*)(PQ + (size_t)r * PQ_STRIDE + col_base) =
                make_float4(acc[i][0], acc[i][1], acc[i][2], acc[i][3]);
        }
    }
}

// ---------------------------------------------------------------------------
// One wave (64 lanes) per edge: score = sum_j relu(P[row,j]+Q[col,j]+b1[j])*W2[j] + b2
// Lane handles 8 j's as two float4s at j0=lane*4 and 256+lane*4 (perfectly coalesced:
// a wave reads one contiguous 2KB row per load pair). Also does segment-max atomically.
// ---------------------------------------------------------------------------
__global__ __launch_bounds__(256) void edge_scores(
    const float* __restrict__ PQ, const float* __restrict__ b1,
    const float* __restrict__ W2, const float* __restrict__ b2,
    const int* __restrict__ row, const int* __restrict__ col,
    float* __restrict__ scores, float* __restrict__ node_max)
{
    const int e    = (blockIdx.x << 2) + (threadIdx.x >> 6);
    const int lane = threadIdx.x & 63;
    if (e >= N_EDGES) return;

    const int r = row[e];
    const int c = col[e];
    const float* __restrict__ p = PQ + (size_t)r * PQ_STRIDE;        // P half
    const float* __restrict__ q = PQ + (size_t)c * PQ_STRIDE + HID;  // Q half
    const int j0 = lane << 2;

    float4 p0 = *(const float4*)(p + j0);
    float4 p1 = *(const float4*)(p + 256 + j0);
    float4 q0 = *(const float4*)(q + j0);
    float4 q1 = *(const float4*)(q + 256 + j0);
    float4 bb0 = *(const float4*)(b1 + j0);
    float4 bb1 = *(const float4*)(b1 + 256 + j0);
    float4 w0 = *(const float4*)(W2 + j0);
    float4 w1 = *(const float4*)(W2 + 256 + j0);

    float s = 0.0f;
    s = fmaf(fmaxf(p0.x + q0.x + bb0.x, 0.0f), w0.x, s);
    s = fmaf(fmaxf(p0.y + q0.y + bb0.y, 0.0f), w0.y, s);
    s = fmaf(fmaxf(p0.z + q0.z + bb0.z, 0.0f), w0.z, s);
    s = fmaf(fmaxf(p0.w + q0.w + bb0.w, 0.0f), w0.w, s);
    s = fmaf(fmaxf(p1.x + q1.x + bb1.x, 0.0f), w1.x, s);
    s = fmaf(fmaxf(p1.y + q1.y + bb1.y, 0.0f), w1.y, s);
    s = fmaf(fmaxf(p1.z + q1.z + bb1.z, 0.0f), w1.z, s);
    s = fmaf(fmaxf(p1.w + q1.w + bb1.w, 0.0f), w1.w, s);

#pragma unroll
    for (int off = 32; off > 0; off >>= 1)
        s += __shfl_down(s, off, 64);

    if (lane == 0) {
        float sc = s + b2[0];
        scores[e] = sc;
        atomicMaxFloat(&node_max[r], sc);
    }
}

// ---------------------------------------------------------------------------
// exp(score - segmax) + segment sum
// ---------------------------------------------------------------------------
__global__ void edge_expsum(
    const float* __restrict__ scores, const int* __restrict__ row,
    const float* __restrict__ node_max, float* __restrict__ e_val,
    float* __restrict__ node_sum)
{
    int e = blockIdx.x * 256 + threadIdx.x;
    if (e >= N_EDGES) return;
    int r = row[e];
    float ev = expf(scores[e] - node_max[r]);
    e_val[e] = ev;
    atomicAdd(&node_sum[r], ev);
}

// ---------------------------------------------------------------------------
// probs -> relaxed bernoulli -> straight-through hard mask -> outputs
// IEEE inf semantics required (probs==1 -> logits=+inf -> y=1); no fast-math.
// ---------------------------------------------------------------------------
__global__ void finalize(
    const float* __restrict__ scores, const float* __restrict__ e_val,
    const float* __restrict__ node_sum, const int* __restrict__ row,
    const float* __restrict__ u, const int* __restrict__ edge_mask,
    const int* __restrict__ hierarchy,
    float* __restrict__ out_y, float* __restrict__ out_mask,
    float* __restrict__ out_causal, float* __restrict__ out_spu)
{
    int e = blockIdx.x * 256 + threadIdx.x;
    if (e >= N_EDGES) return;
    int r = row[e];
    float p = e_val[e] / node_sum[r];
    float logits = logf(p) - log1pf(-p);        // +inf when p==1 (single-edge segment)
    float uu = u[e];
    float L = logf(uu) - log1pf(-uu);
    float t = logits + L;
    float y = 1.0f / (1.0f + expf(-t));         // t=+inf -> 1, t=-inf -> 0
    bool hard = y > 0.5f;                       // y_st forward value is exactly y_hard
    int hv = hierarchy[0];
    int m = hard ? (hv + 1) : edge_mask[e];
    float sc = scores[e];
    out_y[e]      = hard ? 1.0f : 0.0f;
    out_mask[e]   = (float)m;
    out_causal[e] = (m > 0)   ?  sc : 0.0f;
    out_spu[e]    = (m == -1) ? -sc : 0.0f;
}

// ---------------------------------------------------------------------------
extern "C" void kernel_launch(void* const* d_in, const int* in_sizes, int n_in,
                              void* d_out, int out_size, void* d_ws, size_t ws_size,
                              hipStream_t stream) {
    const float* h_ptr = (const float*)d_in[0];
    const float* W1    = (const float*)d_in[1];
    const float* b1    = (const float*)d_in[2];
    const float* W2    = (const float*)d_in[3];
    const float* b2    = (const float*)d_in[4];
    const float* u     = (const float*)d_in[5];
    const int*   row   = (const int*)d_in[6];
    const int*   col   = (const int*)d_in[7];
    const int*   emask = (const int*)d_in[8];
    const int*   hier  = (const int*)d_in[9];

    float* out        = (float*)d_out;
    float* scores     = out;                  // [E]
    float* out_y      = out + (size_t)N_EDGES;     // [E]
    float* out_mask   = out + 2 * (size_t)N_EDGES; // [E] (ints as floats)
    float* out_causal = out + 3 * (size_t)N_EDGES; // [E]
    float* out_spu    = out + 4 * (size_t)N_EDGES; // [E]

    // workspace layout (floats): node_max[20000] node_sum[20000] e_val[320000] PQ[20000*1024]
    float* node_max = (float*)d_ws;
    float* node_sum = node_max + N_NODES;
    float* e_val    = node_sum + N_NODES;
    float* PQ       = e_val + N_EDGES;

    hipLaunchKernelGGL(init_nodes, dim3((N_NODES + 255) / 256), dim3(256), 0, stream,
                       node_max, node_sum);

    dim3 ggrid(PQ_STRIDE / TN, (N_NODES + TM - 1) / TM);  // 16 x 313
    hipLaunchKernelGGL(gemm_pq, ggrid, dim3(256), 0, stream, h_ptr, W1, PQ);

    hipLaunchKernelGGL(edge_scores, dim3(N_EDGES / 4), dim3(256), 0, stream,
                       PQ, b1, W2, b2, row, col, scores, node_max);

    hipLaunchKernelGGL(edge_expsum, dim3((N_EDGES + 255) / 256), dim3(256), 0, stream,
                       scores, row, node_max, e_val, node_sum);

    hipLaunchKernelGGL(finalize, dim3((N_EDGES + 255) / 256), dim3(256), 0, stream,
                       scores, e_val, node_sum, row, u, emask, hier,
                       out_y, out_mask, out_causal, out_spu);
}